// Round 7
// baseline (2060.557 us; speedup 1.0000x reference)
//
#include <hip/hip_runtime.h>

typedef _Float16 half8 __attribute__((ext_vector_type(8)));
typedef float f32x4 __attribute__((ext_vector_type(4)));
typedef unsigned long long ull;

typedef ull      __attribute__((may_alias)) ull_a;
typedef unsigned __attribute__((may_alias)) u32_a;
typedef float4   __attribute__((may_alias)) float4_a;

#define LGKM_BAR() asm volatile("s_waitcnt lgkmcnt(0)" ::: "memory")

#define Bb 256
#define Tt 512
#define NF 64
#define H1u 256
#define H2u 128
#define NGRP 16
#define Bs 16
#define NBLK 64
#define NTHR 256

#define NF1 10   // L1 k-frags (K=320)
#define NF2 12   // L2 k-frags (K=384)
#define NT1 4    // L1 16x16 tiles per wave
#define NT2 2    // L2 tiles per wave

// ws byte offsets
#define OFFB_WF1 0                       // [W16][tt4][f10][lane64] x half8
#define SZB_WF1  (16*4*NF1*64*16)        // 655360
#define OFFB_WF2 (OFFB_WF1+SZB_WF1)      // [W16][tt2][f12][lane64] x half8
#define SZB_WF2  (16*2*NF2*64*16)        // 393216
#define OFFB_BF1 (OFFB_WF2+SZB_WF2)      // [W16][tt4][g4][4] f32
#define SZB_BF1  (16*4*4*4*4)
#define OFFB_BF2 (OFFB_BF1+SZB_BF1)      // [W16][tt2][g4][4] f32
#define SZB_BF2  (16*2*4*4*4)
#define OFFB_PH1 (OFFB_BF2+SZB_BF2)      // [par2][grp16][chunk32][b16][8] fp16 : 8KB/slab
#define SZB_PH1  (2*16*8192)
#define OFFB_PH2 (OFFB_PH1+SZB_PH1)      // [par2][grp16][chunk16][b16][8] fp16 : 4KB/slab
#define SZB_PH2  (2*16*4096)
#define OFFB_STM (OFFB_PH2+SZB_PH2)      // [grp16][64 u32]: S stamps [0..15], R stamps [16..31]
#define SZB_STM  (16*256)

__device__ __forceinline__ float sigf(float x) {
    return 1.0f / (1.0f + __expf(-x));
}
__device__ __forceinline__ float tanhfast(float x) {
    return 2.0f / (1.0f + __expf(-2.0f * x)) - 1.0f;
}

// ---------------- prep: weights -> MFMA A-fragments (fp16), proven rounds 4-5 ----------------
__global__ __launch_bounds__(256) void prep4(
    const float* __restrict__ Wih1, const float* __restrict__ Whh1,
    const float* __restrict__ bih1, const float* __restrict__ bhh1,
    const float* __restrict__ Wih2, const float* __restrict__ Whh2,
    const float* __restrict__ bih2, const float* __restrict__ bhh2,
    char* __restrict__ wsb)
{
    _Float16* wf1 = (_Float16*)(wsb + OFFB_WF1);
    _Float16* wf2 = (_Float16*)(wsb + OFFB_WF2);
    float*    bf1 = (float*)(wsb + OFFB_BF1);
    float*    bf2 = (float*)(wsb + OFFB_BF2);
    const int stride = gridDim.x * blockDim.x;
    const int i0 = blockIdx.x * blockDim.x + threadIdx.x;

    for (int idx = i0; idx < 16*4*NF1*64; idx += stride) {
        const int lane = idx & 63;
        int q = idx >> 6;
        const int f = q % NF1;  q /= NF1;
        const int tt = q & 3;
        const int w  = q >> 2;
        const int r = lane & 15;
        const int unit = w*16 + tt*4 + (r >> 2);
        const int gate = r & 3;
        const int grow = gate * H1u + unit;
        _Float16* dst = wf1 + (size_t)idx * 8;
        #pragma unroll
        for (int e = 0; e < 8; ++e) {
            const int k = f*32 + (lane >> 4)*8 + e;
            const float v = (k < NF) ? Wih1[grow*NF + k]
                                     : Whh1[grow*H1u + (k - NF)];
            dst[e] = (_Float16)v;
        }
    }
    for (int idx = i0; idx < 16*2*NF2*64; idx += stride) {
        const int lane = idx & 63;
        int q = idx >> 6;
        const int f = q % NF2;  q /= NF2;
        const int tt = q & 1;
        const int w  = q >> 1;
        const int r = lane & 15;
        const int unit = w*8 + tt*4 + (r >> 2);
        const int gate = r & 3;
        const int grow = gate * H2u + unit;
        _Float16* dst = wf2 + (size_t)idx * 8;
        #pragma unroll
        for (int e = 0; e < 8; ++e) {
            const int k = f*32 + (lane >> 4)*8 + e;
            const float v = (k < H1u) ? Wih2[grow*H1u + k]
                                      : Whh2[grow*H2u + (k - H1u)];
            dst[e] = (_Float16)v;
        }
    }
    for (int idx = i0; idx < 16*4*4*4; idx += stride) {
        const int reg = idx & 3, lg = (idx >> 2) & 3;
        const int tt = (idx >> 4) & 3, w = idx >> 6;
        const int unit = w*16 + tt*4 + lg;
        const int grow = reg * H1u + unit;
        bf1[idx] = bih1[grow] + bhh1[grow];
    }
    for (int idx = i0; idx < 16*2*4*4; idx += stride) {
        const int reg = idx & 3, lg = (idx >> 2) & 3;
        const int tt = (idx >> 4) & 1, w = idx >> 5;
        const int unit = w*8 + tt*4 + lg;
        const int grow = reg * H2u + unit;
        bf2[idx] = bih2[grow] + bhh2[grow];
    }
}

__device__ __forceinline__ void load_x_frags(half8* xf, const float* __restrict__ x,
                                             int b0, int b, int g, int t)
{
    #pragma unroll
    for (int f = 0; f < 2; ++f) {
        const float* xp = x + (((size_t)(b0 + b)) * Tt + t) * NF + f * 32 + g * 8;
        const float4 lo = *(const float4*)xp;
        const float4 hi = *(const float4*)(xp + 4);
        half8 v;
        v[0] = (_Float16)lo.x; v[1] = (_Float16)lo.y;
        v[2] = (_Float16)lo.z; v[3] = (_Float16)lo.w;
        v[4] = (_Float16)hi.x; v[5] = (_Float16)hi.y;
        v[6] = (_Float16)hi.z; v[7] = (_Float16)hi.w;
        xf[f] = v;
    }
}

// ---------------- persistent recurrence: 64 blocks = 16 groups x 4 slices,
// 16 free-running wave-slots per group, stamp-gated 2-parity exchange ----------------
__global__ __launch_bounds__(NTHR, 1) void lstm_v7(
    const float* __restrict__ x, char* wsb, float* __restrict__ out)
{
    __shared__ char ldsraw[4 * 2048];    // per-wave 2KB: h1@0 (512B) | h2@512 (256B) | out@1024 (512B f32)

    const int tid   = threadIdx.x;
    const int w     = tid >> 6;
    const int lane  = tid & 63;
    const int g     = lane >> 4;
    const int b     = lane & 15;
    const int grp   = blockIdx.x & 15;
    const int slice = blockIdx.x >> 4;
    const int W     = slice * 4 + w;
    const int b0    = grp * Bs;

    const _Float16* wf1g = (const _Float16*)(wsb + OFFB_WF1);
    const _Float16* wf2g = (const _Float16*)(wsb + OFFB_WF2);
    const float*    bf1g = (const float*)(wsb + OFFB_BF1);
    const float*    bf2g = (const float*)(wsb + OFFB_BF2);
    ull*            ph1  = (ull*)(wsb + OFFB_PH1);
    ull*            ph2  = (ull*)(wsb + OFFB_PH2);
    unsigned*       pu2  = (unsigned*)(wsb + OFFB_PH2);
    unsigned*       stm  = (unsigned*)(wsb + OFFB_STM) + grp * 64;

    char* myl = ldsraw + w * 2048;
    _Float16* l_h1 = (_Float16*)(myl);
    _Float16* l_h2 = (_Float16*)(myl + 512);
    float*    l_o  = (float*)(myl + 1024);

    // ---- one-time: weight fragments + biases -> VGPRs ----
    half8 wA1[NT1][NF1];
    half8 wA2[NT2][NF2];
    #pragma unroll
    for (int tt = 0; tt < NT1; ++tt)
        #pragma unroll
        for (int f = 0; f < NF1; ++f)
            wA1[tt][f] = *(const half8*)(wf1g + ((size_t)(((W*4 + tt)*NF1 + f) * 64 + lane)) * 8);
    #pragma unroll
    for (int tt = 0; tt < NT2; ++tt)
        #pragma unroll
        for (int f = 0; f < NF2; ++f)
            wA2[tt][f] = *(const half8*)(wf2g + ((size_t)(((W*2 + tt)*NF2 + f) * 64 + lane)) * 8);

    f32x4 bias1[NT1], bias2[NT2];
    #pragma unroll
    for (int tt = 0; tt < NT1; ++tt)
        bias1[tt] = *(const f32x4*)(bf1g + ((W*4 + tt)*4 + g) * 4);
    #pragma unroll
    for (int tt = 0; tt < NT2; ++tt)
        bias2[tt] = *(const f32x4*)(bf2g + ((W*2 + tt)*4 + g) * 4);

    float c1s[NT1] = {0.f, 0.f, 0.f, 0.f};
    float c2s[NT2] = {0.f, 0.f};

    // h-state fragments live in regs; zeros at t=0 (h1(-1)=h2(-1)=0)
    half8 hz = {};
    half8 hf[8]  = {hz, hz, hz, hz, hz, hz, hz, hz};
    half8 h2f[4] = {hz, hz, hz, hz};
    half8 xf[2];
    load_x_frags(xf, x, b0, b, g, 0);

    for (int t = 0; t <= Tt; ++t) {
        // ================ L1: compute h1(t) ================
        if (t < Tt) {
            f32x4 acc[NT1] = {};
            #pragma unroll
            for (int tt = 0; tt < NT1; ++tt) {
                acc[tt] = __builtin_amdgcn_mfma_f32_16x16x32_f16(wA1[tt][0], xf[0], acc[tt], 0, 0, 0);
                acc[tt] = __builtin_amdgcn_mfma_f32_16x16x32_f16(wA1[tt][1], xf[1], acc[tt], 0, 0, 0);
            }
            #pragma unroll
            for (int f = 0; f < 8; ++f)
                #pragma unroll
                for (int tt = 0; tt < NT1; ++tt)
                    acc[tt] = __builtin_amdgcn_mfma_f32_16x16x32_f16(wA1[tt][2 + f], hf[f], acc[tt], 0, 0, 0);
            #pragma unroll
            for (int tt = 0; tt < NT1; ++tt) {
                const float iv = sigf(acc[tt][0] + bias1[tt][0]);
                const float fv = sigf(acc[tt][1] + bias1[tt][1]);
                const float gv = tanhfast(acc[tt][2] + bias1[tt][2]);
                const float ov = sigf(acc[tt][3] + bias1[tt][3]);
                const float c = fmaf(fv, c1s[tt], iv * gv);
                c1s[tt] = c;
                const float h = ov * tanhfast(c);
                const int ul = tt * 4 + g;                        // unit within wave tile
                l_h1[((ul >> 3) * 16 + b) * 8 + (ul & 7)] = (_Float16)h;
            }
            // pin LDS writes before type-punned readback (TBAA fence + hw wait)
            LGKM_BAR();
            // wave-coalesced h1(t) store: 512B contiguous (8B/lane)
            {
                const ull v = *(const ull_a*)(l_h1 + lane * 4);
                const size_t di = ((size_t)((t & 1) * 16 + grp)) * 1024 + W * 64 + lane;
                __hip_atomic_store(ph1 + di, v, __ATOMIC_RELAXED, __HIP_MEMORY_SCOPE_AGENT);
            }
        }
        // ================ L2: compute h2(t-1) (overlaps h1 store flight) ================
        if (t >= 1) {
            f32x4 acc[NT2] = {};
            #pragma unroll
            for (int f = 0; f < 8; ++f)
                #pragma unroll
                for (int tt = 0; tt < NT2; ++tt)
                    acc[tt] = __builtin_amdgcn_mfma_f32_16x16x32_f16(wA2[tt][f], hf[f], acc[tt], 0, 0, 0);
            #pragma unroll
            for (int f = 0; f < 4; ++f)
                #pragma unroll
                for (int tt = 0; tt < NT2; ++tt)
                    acc[tt] = __builtin_amdgcn_mfma_f32_16x16x32_f16(wA2[tt][8 + f], h2f[f], acc[tt], 0, 0, 0);
            #pragma unroll
            for (int tt = 0; tt < NT2; ++tt) {
                const float iv = sigf(acc[tt][0] + bias2[tt][0]);
                const float fv = sigf(acc[tt][1] + bias2[tt][1]);
                const float gv = tanhfast(acc[tt][2] + bias2[tt][2]);
                const float ov = sigf(acc[tt][3] + bias2[tt][3]);
                const float c = fmaf(fv, c2s[tt], iv * gv);
                c2s[tt] = c;
                const float h = ov * tanhfast(c);
                const int ul = tt * 4 + g;
                if (t < Tt) l_h2[b * 8 + ul] = (_Float16)h;
                l_o[b * 8 + ul] = h;
            }
            // pin LDS writes (l_h2 + l_o) before punned readbacks
            LGKM_BAR();
            if (t < Tt) {   // wave-coalesced h2(t-1) store: 256B contiguous (4B/lane)
                const unsigned v = *(const u32_a*)((const _Float16*)l_h2 + lane * 2);
                const size_t di = ((size_t)(((t + 1) & 1) * 16 + grp)) * 1024 + W * 64 + lane;
                __hip_atomic_store(pu2 + di, v, __ATOMIC_RELAXED, __HIP_MEMORY_SCOPE_AGENT);
            }
        }
        // ================ drain own data stores, publish S stamp ================
        if (t < Tt) {
            asm volatile("s_waitcnt vmcnt(0)" ::: "memory");
            if (lane == 0)
                __hip_atomic_store(&stm[W], (unsigned)(t + 1),
                                   __ATOMIC_RELAXED, __HIP_MEMORY_SCOPE_AGENT);
        }
        // ================ out writes (fire-and-forget) + x prefetch ================
        if (t >= 1 && lane < 32) {
            const int s_ = t - 1;
            const int bb = lane >> 1, q = lane & 1;
            const float4 ov = *(const float4_a*)(l_o + bb * 8 + q * 4);
            *(float4*)&out[((size_t)(b0 + bb) * Tt + s_) * H2u + W * 8 + q * 4] = ov;
            if (s_ == Tt - 1)
                *(float4*)&out[(size_t)Bb * Tt * H2u + (size_t)(b0 + bb) * H2u + W * 8 + q * 4] = ov;
        }
        if (t + 1 < Tt) load_x_frags(xf, x, b0, b, g, t + 1);
        // ================ poll stamps, load h frags for t+1, publish R ================
        if (t < Tt) {
            const int si = lane & 31;
            const unsigned need = (si < 16) ? (unsigned)(t + 1) : (unsigned)t;
            const unsigned* sp = stm + si;
            for (;;) {
                const unsigned v = __hip_atomic_load(sp, __ATOMIC_RELAXED, __HIP_MEMORY_SCOPE_AGENT);
                if (__all((int)(v >= need))) break;
                __builtin_amdgcn_s_sleep(1);
            }
            const size_t base1 = ((size_t)((t & 1) * 16 + grp)) * 1024;
            #pragma unroll
            for (int f = 0; f < 8; ++f) {
                const size_t a = base1 + (size_t)(4 * f + g) * 32 + b * 2;
                union { ull q[2]; half8 h; } u;
                u.q[0] = __hip_atomic_load(ph1 + a,     __ATOMIC_RELAXED, __HIP_MEMORY_SCOPE_AGENT);
                u.q[1] = __hip_atomic_load(ph1 + a + 1, __ATOMIC_RELAXED, __HIP_MEMORY_SCOPE_AGENT);
                hf[f] = u.h;
            }
            const size_t base2 = ((size_t)(((t + 1) & 1) * 16 + grp)) * 512;
            #pragma unroll
            for (int f = 0; f < 4; ++f) {
                const size_t a = base2 + (size_t)(4 * f + g) * 32 + b * 2;
                union { ull q[2]; half8 h; } u;
                u.q[0] = __hip_atomic_load(ph2 + a,     __ATOMIC_RELAXED, __HIP_MEMORY_SCOPE_AGENT);
                u.q[1] = __hip_atomic_load(ph2 + a + 1, __ATOMIC_RELAXED, __HIP_MEMORY_SCOPE_AGENT);
                h2f[f] = u.h;
            }
            asm volatile("s_waitcnt vmcnt(0)" ::: "memory");
            if (lane == 0)
                __hip_atomic_store(&stm[16 + W], (unsigned)(t + 1),
                                   __ATOMIC_RELAXED, __HIP_MEMORY_SCOPE_AGENT);
        }
    }
}

extern "C" void kernel_launch(void* const* d_in, const int* in_sizes, int n_in,
                              void* d_out, int out_size, void* d_ws, size_t ws_size,
                              hipStream_t stream) {
    const float* x    = (const float*)d_in[0];
    const float* Wih1 = (const float*)d_in[1];
    const float* Whh1 = (const float*)d_in[2];
    const float* bih1 = (const float*)d_in[3];
    const float* bhh1 = (const float*)d_in[4];
    const float* Wih2 = (const float*)d_in[5];
    const float* Whh2 = (const float*)d_in[6];
    const float* bih2 = (const float*)d_in[7];
    const float* bhh2 = (const float*)d_in[8];
    char*  wsb = (char*)d_ws;
    float* out = (float*)d_out;

    prep4<<<256, 256, 0, stream>>>(Wih1, Whh1, bih1, bhh1,
                                   Wih2, Whh2, bih2, bhh2, wsb);
    // zero h panels + stamps every launch (stamps are monotonic within one run)
    hipMemsetAsync((void*)(wsb + OFFB_PH1), 0, SZB_PH1 + SZB_PH2 + SZB_STM, stream);
    lstm_v7<<<NBLK, NTHR, 0, stream>>>(x, wsb, out);
}